// Round 5
// baseline (601.279 us; speedup 1.0000x reference)
//
#include <hip/hip_runtime.h>
#include <cstdint>
#include <cstddef>
#include <math.h>

#define N_NODES 100000
#define N_EDGES 1600000
#define DIM 128
#define DOUT 40
#define BN_EPS 1e-5f

typedef __attribute__((ext_vector_type(8))) short bf16x8;
typedef __attribute__((ext_vector_type(4))) float f32x4;

__device__ __forceinline__ float bf2f(uint u16shifted) {
    union { uint i; float f; } c; c.i = u16shifted; return c.f;
}
__device__ __forceinline__ ushort f2bf(float f) {
    union { float f; uint i; } c; c.f = f;
    uint i = c.i;
    uint lsb = (i >> 16) & 1u;
    i += 0x7FFFu + lsb;
    return (ushort)(i >> 16);
}
// apply BN+ReLU to a packed pair of bf16 given per-col scale/shift, repack
__device__ __forceinline__ uint bnpack(uint u, float s0, float h0, float s1, float h1) {
    float lo = fmaxf(bf2f(u << 16) * s0 + h0, 0.f);
    float hi = fmaxf(bf2f(u & 0xFFFF0000u) * s1 + h1, 0.f);
    return (uint)f2bf(lo) | ((uint)f2bf(hi) << 16);
}

// ---------------- convert x -> bf16 ----------------
__global__ __launch_bounds__(256) void k_cvt(const float* __restrict__ in,
                                             ushort* __restrict__ out, int n4) {
    int i = blockIdx.x * blockDim.x + threadIdx.x;
    int stride = gridDim.x * blockDim.x;
    for (; i < n4; i += stride) {
        float4 v = reinterpret_cast<const float4*>(in)[i];
        ushort4 o;
        o.x = f2bf(v.x); o.y = f2bf(v.y); o.z = f2bf(v.z); o.w = f2bf(v.w);
        reinterpret_cast<ushort4*>(out)[i] = o;
    }
}

// ---------------- build Wcat[n][k] = k<128 ? W[k][n] : R[k-128][n], bf16, zero-pad n>=NW ----
__global__ void k_wcat(const float* __restrict__ W, const float* __restrict__ R,
                       ushort* __restrict__ out, int NW) {
    int idx = blockIdx.x * 256 + threadIdx.x;  // grid = Nout blocks
    int n = idx >> 8, k = idx & 255;
    float v = 0.f;
    if (n < NW) v = (k < 128) ? W[k * NW + n] : R[(k - 128) * NW + n];
    out[idx] = f2bf(v);
}

// ---------------- CSR build, dst-range partitioned (8 groups ~ XCDs) ----------------
#define RANGE_SZ (N_NODES / 8)                   // 12500
#define FILL_CHUNKS 512                          // blocks per group
#define EDGES_PER_CHUNK (N_EDGES / FILL_CHUNKS)  // 3125

__global__ __launch_bounds__(256) void k_count_p(const int* __restrict__ ei,
                                                 int* __restrict__ counts) {
    int g = blockIdx.x & 7;
    int chunk = blockIdx.x >> 3;
    int lo = g * RANGE_SZ, hi = lo + RANGE_SZ;
    int e0 = chunk * EDGES_PER_CHUNK, e1 = e0 + EDGES_PER_CHUNK;
    for (int e = e0 + threadIdx.x; e < e1; e += 256) {
        int d = ei[N_EDGES + e];
        if (d >= lo && d < hi) atomicAdd(&counts[d], 1);
    }
}

__global__ __launch_bounds__(256) void k_fill_p(const int* __restrict__ ei,
                                                int* __restrict__ cursor,
                                                int* __restrict__ csr) {
    int g = blockIdx.x & 7;
    int chunk = blockIdx.x >> 3;
    int lo = g * RANGE_SZ, hi = lo + RANGE_SZ;
    int e0 = chunk * EDGES_PER_CHUNK, e1 = e0 + EDGES_PER_CHUNK;
    for (int e = e0 + threadIdx.x; e < e1; e += 256) {
        int d = ei[N_EDGES + e];
        if (d >= lo && d < hi) {
            int s = ei[e];
            int pos = atomicAdd(&cursor[d], 1);  // cursor pre-loaded with rowstart
            csr[pos] = s;
        }
    }
}

__global__ void k_scan1(int* __restrict__ data, int* __restrict__ bsums) {
    __shared__ int ts[256];
    int base = blockIdx.x * 1024;
    int t = threadIdx.x;
    int v[4]; int s = 0;
#pragma unroll
    for (int i = 0; i < 4; i++) {
        int idx = base + t * 4 + i;
        v[i] = (idx < N_NODES) ? data[idx] : 0;
        s += v[i];
    }
    ts[t] = s; __syncthreads();
    for (int off = 1; off < 256; off <<= 1) {
        int own = ts[t];
        int add = (t >= off) ? ts[t - off] : 0;
        __syncthreads();
        ts[t] = own + add;
        __syncthreads();
    }
    int incl = ts[t];
    int run = incl - s;
#pragma unroll
    for (int i = 0; i < 4; i++) {
        int idx = base + t * 4 + i;
        if (idx < N_NODES) data[idx] = run;
        run += v[i];
    }
    if (t == 255) bsums[blockIdx.x] = incl;
}

__global__ void k_scan2(int* bsums, int nb) {
    if (threadIdx.x == 0) {
        int run = 0;
        for (int b = 0; b < nb; b++) { int x = bsums[b]; bsums[b] = run; run += x; }
    }
}

__global__ void k_scan3(int* __restrict__ data, const int* __restrict__ bsums) {
    int base = blockIdx.x * 1024;
    int add = bsums[blockIdx.x];
    int t = threadIdx.x;
#pragma unroll
    for (int i = 0; i < 4; i++) {
        int idx = base + t * 4 + i;
        if (idx < N_NODES) data[idx] += add;
    }
    if (blockIdx.x == 0 && t == 0) data[N_NODES] = N_EDGES;
}

// ---------------- mean aggregation, bf16, 4 edges in flight, optional fused BN+ReLU --------
// one wave per node; lane = slot(0..3) x colgroup(0..15); each lane loads uint4 = 8 bf16 cols
__global__ __launch_bounds__(256) void k_agg_bf(const ushort* __restrict__ cur,
                                                const int* __restrict__ rowstart,
                                                const int* __restrict__ csr,
                                                ushort* __restrict__ out,
                                                const float* __restrict__ scale,
                                                const float* __restrict__ shift,
                                                int hasbn) {
    int wid = (blockIdx.x * blockDim.x + threadIdx.x) >> 6;
    int lane = threadIdx.x & 63;
    if (wid >= N_NODES) return;
    int beg = rowstart[wid];
    int end = rowstart[wid + 1];
    int slot = lane >> 4;   // which edge within a group of 4
    int cg = lane & 15;     // column group: cols cg*8 .. cg*8+7
    float sc0 = 1.f, sc1 = 1.f, sc2 = 1.f, sc3 = 1.f, sc4 = 1.f, sc5 = 1.f, sc6 = 1.f, sc7 = 1.f;
    float sh0 = 0.f, sh1 = 0.f, sh2 = 0.f, sh3 = 0.f, sh4 = 0.f, sh5 = 0.f, sh6 = 0.f, sh7 = 0.f;
    if (hasbn) {
        int c0 = cg * 8;
        sc0 = scale[c0 + 0]; sc1 = scale[c0 + 1]; sc2 = scale[c0 + 2]; sc3 = scale[c0 + 3];
        sc4 = scale[c0 + 4]; sc5 = scale[c0 + 5]; sc6 = scale[c0 + 6]; sc7 = scale[c0 + 7];
        sh0 = shift[c0 + 0]; sh1 = shift[c0 + 1]; sh2 = shift[c0 + 2]; sh3 = shift[c0 + 3];
        sh4 = shift[c0 + 4]; sh5 = shift[c0 + 5]; sh6 = shift[c0 + 6]; sh7 = shift[c0 + 7];
    }
    const uint4* base = reinterpret_cast<const uint4*>(cur);  // row = 16 x uint4
    float a0 = 0.f, a1 = 0.f, a2 = 0.f, a3 = 0.f, a4 = 0.f, a5 = 0.f, a6 = 0.f, a7 = 0.f;
#pragma unroll 2
    for (int e = beg + slot; e < end; e += 4) {
        int s = csr[e];
        uint4 u = base[(size_t)s * 16 + cg];
        float v0 = bf2f(u.x << 16), v1 = bf2f(u.x & 0xFFFF0000u);
        float v2 = bf2f(u.y << 16), v3 = bf2f(u.y & 0xFFFF0000u);
        float v4 = bf2f(u.z << 16), v5 = bf2f(u.z & 0xFFFF0000u);
        float v6 = bf2f(u.w << 16), v7 = bf2f(u.w & 0xFFFF0000u);
        if (hasbn) {
            v0 = fmaxf(v0 * sc0 + sh0, 0.f); v1 = fmaxf(v1 * sc1 + sh1, 0.f);
            v2 = fmaxf(v2 * sc2 + sh2, 0.f); v3 = fmaxf(v3 * sc3 + sh3, 0.f);
            v4 = fmaxf(v4 * sc4 + sh4, 0.f); v5 = fmaxf(v5 * sc5 + sh5, 0.f);
            v6 = fmaxf(v6 * sc6 + sh6, 0.f); v7 = fmaxf(v7 * sc7 + sh7, 0.f);
        }
        a0 += v0; a1 += v1; a2 += v2; a3 += v3;
        a4 += v4; a5 += v5; a6 += v6; a7 += v7;
    }
    // combine the 4 slots: lanes l, l^16, l^32
#pragma unroll
    for (int off = 16; off < 64; off <<= 1) {
        a0 += __shfl_xor(a0, off, 64); a1 += __shfl_xor(a1, off, 64);
        a2 += __shfl_xor(a2, off, 64); a3 += __shfl_xor(a3, off, 64);
        a4 += __shfl_xor(a4, off, 64); a5 += __shfl_xor(a5, off, 64);
        a6 += __shfl_xor(a6, off, 64); a7 += __shfl_xor(a7, off, 64);
    }
    if (slot == 0) {
        int deg = end - beg;
        float inv = 1.0f / (float)(deg > 1 ? deg : 1);
        uint4 o;
        o.x = (uint)f2bf(a0 * inv) | ((uint)f2bf(a1 * inv) << 16);
        o.y = (uint)f2bf(a2 * inv) | ((uint)f2bf(a3 * inv) << 16);
        o.z = (uint)f2bf(a4 * inv) | ((uint)f2bf(a5 * inv) << 16);
        o.w = (uint)f2bf(a6 * inv) | ((uint)f2bf(a7 * inv) << 16);
        reinterpret_cast<uint4*>(out)[(size_t)wid * 16 + cg] = o;
    }
}

// ---------------- MFMA GEMM: out[M,128] = mean@W + bnrelu(cur)@R + b ------------------------
// 128x128 tile, 256 threads = 4 waves as 2x2, each wave 64x64 (4x4 frags of 16x16x32)
// in-place safe for out==mean; Ac tile gets optional BN+ReLU applied at staging
__global__ __launch_bounds__(256) void k_gemm_mfma(const ushort* __restrict__ Am,
                                                   const ushort* __restrict__ Ac,
                                                   const ushort* __restrict__ Wcat, // [128][256]
                                                   const float* __restrict__ bias,
                                                   const float* __restrict__ scale,
                                                   const float* __restrict__ shift,
                                                   int hasbn,
                                                   ushort* __restrict__ out) {
    __shared__ ushort As[128 * 40];  // 128 rows x 32 k, padded stride 40 (80 B)
    __shared__ ushort Bs[128 * 40];  // 128 cols x 32 k
    int tid = threadIdx.x;
    int wid = tid >> 6, lane = tid & 63;
    int wr = wid >> 1, wc = wid & 1;
    int l15 = lane & 15, lhi = lane >> 4;
    int row0 = blockIdx.x * 128;

    f32x4 acc[4][4];
#pragma unroll
    for (int m = 0; m < 4; m++)
#pragma unroll
        for (int n = 0; n < 4; n++) acc[m][n] = (f32x4){0.f, 0.f, 0.f, 0.f};

    for (int ks = 0; ks < 8; ++ks) {
        int kg = ks * 32;
        bool self = (kg >= 128);
        const ushort* Asrc = self ? Ac : Am;
        int ka = kg & 127;
        bool doBN = self && hasbn;
        __syncthreads();
#pragma unroll
        for (int h = 0; h < 2; ++h) {
            int c = tid + h * 256;
            int row = c >> 2, q = c & 3;
            int gr = row0 + row;
            uint4 v = {0, 0, 0, 0};
            if (gr < N_NODES)
                v = *reinterpret_cast<const uint4*>(Asrc + (size_t)gr * 128 + ka + q * 8);
            if (doBN) {
                int cc = ka + q * 8;
                v.x = bnpack(v.x, scale[cc + 0], shift[cc + 0], scale[cc + 1], shift[cc + 1]);
                v.y = bnpack(v.y, scale[cc + 2], shift[cc + 2], scale[cc + 3], shift[cc + 3]);
                v.z = bnpack(v.z, scale[cc + 4], shift[cc + 4], scale[cc + 5], shift[cc + 5]);
                v.w = bnpack(v.w, scale[cc + 6], shift[cc + 6], scale[cc + 7], shift[cc + 7]);
            }
            *reinterpret_cast<uint4*>(&As[row * 40 + q * 8]) = v;
        }
#pragma unroll
        for (int h = 0; h < 2; ++h) {
            int c = tid + h * 256;
            int n = c >> 2, q = c & 3;
            *reinterpret_cast<uint4*>(&Bs[n * 40 + q * 8]) =
                *reinterpret_cast<const uint4*>(Wcat + n * 256 + kg + q * 8);
        }
        __syncthreads();
        bf16x8 a[4], b[4];
#pragma unroll
        for (int m = 0; m < 4; m++)
            a[m] = *reinterpret_cast<bf16x8*>(&As[(wr * 64 + m * 16 + l15) * 40 + lhi * 8]);
#pragma unroll
        for (int n = 0; n < 4; n++)
            b[n] = *reinterpret_cast<bf16x8*>(&Bs[(wc * 64 + n * 16 + l15) * 40 + lhi * 8]);
#pragma unroll
        for (int m = 0; m < 4; m++)
#pragma unroll
            for (int n = 0; n < 4; n++)
                acc[m][n] = __builtin_amdgcn_mfma_f32_16x16x32_bf16(a[m], b[n], acc[m][n], 0, 0, 0);
    }
    // epilogue: + bias, bf16 store
#pragma unroll
    for (int m = 0; m < 4; m++) {
        int rbase = row0 + wr * 64 + m * 16 + lhi * 4;
#pragma unroll
        for (int n = 0; n < 4; n++) {
            int col = wc * 64 + n * 16 + l15;
            float bv = bias[col];
#pragma unroll
            for (int j = 0; j < 4; j++) {
                int gr = rbase + j;
                if (gr < N_NODES) out[(size_t)gr * 128 + col] = f2bf(acc[m][n][j] + bv);
            }
        }
    }
}

// ---------------- layer-3 MFMA GEMM + bias + log_softmax fused ----------------
// 128 rows x 48 cols (40 padded to 48); 4 waves, wave w: rows w*32..+31 (2 frags), 3 col frags
__global__ __launch_bounds__(256) void k_gemm40_mfma(const ushort* __restrict__ Am,
                                                     const ushort* __restrict__ Ac,
                                                     const ushort* __restrict__ Wcat, // [48][256]
                                                     const float* __restrict__ bias,  // [40]
                                                     const float* __restrict__ scale,
                                                     const float* __restrict__ shift,
                                                     float* __restrict__ out) {
    __shared__ ushort As[128 * 40];
    __shared__ ushort Bs[48 * 40];
    int tid = threadIdx.x;
    int w = tid >> 6, lane = tid & 63;
    int l15 = lane & 15, lhi = lane >> 4;
    int row0 = blockIdx.x * 128;

    f32x4 acc[2][3];
#pragma unroll
    for (int m = 0; m < 2; m++)
#pragma unroll
        for (int n = 0; n < 3; n++) acc[m][n] = (f32x4){0.f, 0.f, 0.f, 0.f};

    for (int ks = 0; ks < 8; ++ks) {
        int kg = ks * 32;
        bool self = (kg >= 128);
        const ushort* Asrc = self ? Ac : Am;
        int ka = kg & 127;
        __syncthreads();
#pragma unroll
        for (int h = 0; h < 2; ++h) {
            int c = tid + h * 256;
            int row = c >> 2, q = c & 3;
            int gr = row0 + row;
            uint4 v = {0, 0, 0, 0};
            if (gr < N_NODES)
                v = *reinterpret_cast<const uint4*>(Asrc + (size_t)gr * 128 + ka + q * 8);
            if (self) {
                int cc = ka + q * 8;
                v.x = bnpack(v.x, scale[cc + 0], shift[cc + 0], scale[cc + 1], shift[cc + 1]);
                v.y = bnpack(v.y, scale[cc + 2], shift[cc + 2], scale[cc + 3], shift[cc + 3]);
                v.z = bnpack(v.z, scale[cc + 4], shift[cc + 4], scale[cc + 5], shift[cc + 5]);
                v.w = bnpack(v.w, scale[cc + 6], shift[cc + 6], scale[cc + 7], shift[cc + 7]);
            }
            *reinterpret_cast<uint4*>(&As[row * 40 + q * 8]) = v;
        }
        if (tid < 192) {
            int n = tid >> 2, q = tid & 3;
            *reinterpret_cast<uint4*>(&Bs[n * 40 + q * 8]) =
                *reinterpret_cast<const uint4*>(Wcat + n * 256 + kg + q * 8);
        }
        __syncthreads();
        bf16x8 a[2], b[3];
#pragma unroll
        for (int m = 0; m < 2; m++)
            a[m] = *reinterpret_cast<bf16x8*>(&As[(w * 32 + m * 16 + l15) * 40 + lhi * 8]);
#pragma unroll
        for (int n = 0; n < 3; n++)
            b[n] = *reinterpret_cast<bf16x8*>(&Bs[(n * 16 + l15) * 40 + lhi * 8]);
#pragma unroll
        for (int m = 0; m < 2; m++)
#pragma unroll
            for (int n = 0; n < 3; n++)
                acc[m][n] = __builtin_amdgcn_mfma_f32_16x16x32_bf16(a[m], b[n], acc[m][n], 0, 0, 0);
    }
    // epilogue: bias + log_softmax per row (row lives in a 16-lane group)
    float b0 = bias[l15];
    float b1 = bias[16 + l15];
    float b2 = (l15 < 8) ? bias[32 + l15] : 0.f;
#pragma unroll
    for (int m = 0; m < 2; m++) {
#pragma unroll
        for (int j = 0; j < 4; j++) {
            int grow = row0 + w * 32 + m * 16 + lhi * 4 + j;
            float v0 = acc[m][0][j] + b0;
            float v1 = acc[m][1][j] + b1;
            float v2 = (l15 < 8) ? (acc[m][2][j] + b2) : -INFINITY;
            float mx = fmaxf(fmaxf(v0, v1), v2);
#pragma unroll
            for (int off = 1; off < 16; off <<= 1) mx = fmaxf(mx, __shfl_xor(mx, off, 64));
            float s = expf(v0 - mx) + expf(v1 - mx) + ((l15 < 8) ? expf(v2 - mx) : 0.f);
#pragma unroll
            for (int off = 1; off < 16; off <<= 1) s += __shfl_xor(s, off, 64);
            float lg = mx + logf(s);
            if (grow < N_NODES) {
                out[(size_t)grow * DOUT + l15] = v0 - lg;
                out[(size_t)grow * DOUT + 16 + l15] = v1 - lg;
                if (l15 < 8) out[(size_t)grow * DOUT + 32 + l15] = v2 - lg;
            }
        }
    }
}

// ---------------- BN stats on bf16 H (pre-BN) ----------------
__global__ __launch_bounds__(256) void k_colstats_bf(const ushort* __restrict__ H,
                                                     float* __restrict__ sum,
                                                     float* __restrict__ sumsq) {
    int tid = threadIdx.x;
    int cg = tid & 31;   // cols cg*4..cg*4+3
    int rr = tid >> 5;   // 0..7
    float s[4] = {0, 0, 0, 0}, s2[4] = {0, 0, 0, 0};
    for (int r = blockIdx.x * 8 + rr; r < N_NODES; r += gridDim.x * 8) {
        uint2 u = *reinterpret_cast<const uint2*>(H + (size_t)r * 128 + cg * 4);
        float f0 = bf2f(u.x << 16), f1 = bf2f(u.x & 0xFFFF0000u);
        float f2 = bf2f(u.y << 16), f3 = bf2f(u.y & 0xFFFF0000u);
        s[0] += f0; s2[0] += f0 * f0;
        s[1] += f1; s2[1] += f1 * f1;
        s[2] += f2; s2[2] += f2 * f2;
        s[3] += f3; s2[3] += f3 * f3;
    }
    __shared__ float ls[256][4], ls2[256][4];
#pragma unroll
    for (int i = 0; i < 4; i++) { ls[tid][i] = s[i]; ls2[tid][i] = s2[i]; }
    __syncthreads();
    if (tid < 32) {
#pragma unroll
        for (int j = 1; j < 8; j++)
#pragma unroll
            for (int i = 0; i < 4; i++) { s[i] += ls[j * 32 + tid][i]; s2[i] += ls2[j * 32 + tid][i]; }
#pragma unroll
        for (int i = 0; i < 4; i++) {
            atomicAdd(&sum[tid * 4 + i], s[i]);
            atomicAdd(&sumsq[tid * 4 + i], s2[i]);
        }
    }
}

__global__ void k_bnfin(const float* __restrict__ sum, const float* __restrict__ sumsq,
                        const float* __restrict__ g, const float* __restrict__ be,
                        float* __restrict__ scale, float* __restrict__ shift) {
    int c = threadIdx.x;
    if (c < DIM) {
        float mu = sum[c] * (1.0f / N_NODES);
        float var = sumsq[c] * (1.0f / N_NODES) - mu * mu;
        float sc = g[c] * rsqrtf(var + BN_EPS);
        scale[c] = sc;
        shift[c] = be[c] - mu * sc;
    }
}

// ---------------- launch ----------------
extern "C" void kernel_launch(void* const* d_in, const int* in_sizes, int n_in,
                              void* d_out, int out_size, void* d_ws, size_t ws_size,
                              hipStream_t stream) {
    const float* x = (const float*)d_in[0];
    const int* ei = (const int*)d_in[1];
    const float* w1 = (const float*)d_in[2];
    const float* r1 = (const float*)d_in[3];
    const float* b1 = (const float*)d_in[4];
    const float* g1 = (const float*)d_in[5];
    const float* be1 = (const float*)d_in[6];
    const float* w2 = (const float*)d_in[7];
    const float* r2 = (const float*)d_in[8];
    const float* b2 = (const float*)d_in[9];
    const float* g2 = (const float*)d_in[10];
    const float* be2 = (const float*)d_in[11];
    const float* w3 = (const float*)d_in[12];
    const float* r3 = (const float*)d_in[13];
    const float* b3 = (const float*)d_in[14];
    float* out = (float*)d_out;

    const size_t NF = (size_t)N_NODES * DIM;  // 12.8M
    ushort* Xb = (ushort*)d_ws;
    ushort* Ab = Xb + NF;
    ushort* Bb = Ab + NF;
    ushort* Wc1 = Bb + NF;             // 128*256
    ushort* Wc2 = Wc1 + 128 * 256;
    ushort* Wc3 = Wc2 + 128 * 256;     // 48*256
    int* rowstart = (int*)(Wc3 + 48 * 256);
    int* csr = rowstart + (N_NODES + 1);
    int* cursor = csr + N_EDGES;
    int* bsums = cursor + N_NODES;
    float* colsum = (float*)(bsums + 128);
    float* colsumsq = colsum + 128;
    float* scaleS = colsumsq + 128;
    float* shiftS = scaleS + 128;
    size_t needed = (size_t)((char*)(shiftS + 128) - (char*)d_ws);
    if (ws_size < needed) return;

    const int SCAN_BLOCKS = (N_NODES + 1023) / 1024;  // 98
    const int AGG_BLOCKS = N_NODES / 4;               // 25000
    const int GEMM_BLOCKS = (N_NODES + 127) / 128;    // 782
    const int FILL_BLOCKS = FILL_CHUNKS * 8;          // 4096

    // conversions
    k_cvt<<<2048, 256, 0, stream>>>(x, Xb, (int)(NF / 4));
    k_wcat<<<128, 256, 0, stream>>>(w1, r1, Wc1, 128);
    k_wcat<<<128, 256, 0, stream>>>(w2, r2, Wc2, 128);
    k_wcat<<<48, 256, 0, stream>>>(w3, r3, Wc3, DOUT);

    // CSR build (dst-range partitioned)
    hipMemsetAsync(rowstart, 0, sizeof(int) * (N_NODES + 1), stream);
    k_count_p<<<FILL_BLOCKS, 256, 0, stream>>>(ei, rowstart);
    k_scan1<<<SCAN_BLOCKS, 256, 0, stream>>>(rowstart, bsums);
    k_scan2<<<1, 64, 0, stream>>>(bsums, SCAN_BLOCKS);
    k_scan3<<<SCAN_BLOCKS, 256, 0, stream>>>(rowstart, bsums);
    hipMemcpyAsync(cursor, rowstart, sizeof(int) * N_NODES, hipMemcpyDeviceToDevice, stream);
    k_fill_p<<<FILL_BLOCKS, 256, 0, stream>>>(ei, cursor, csr);

    // ---- layer 1 ----  (h1 = gemm output, PRE-BN, stored in Ab)
    k_agg_bf<<<AGG_BLOCKS, 256, 0, stream>>>(Xb, rowstart, csr, Ab, nullptr, nullptr, 0);
    k_gemm_mfma<<<GEMM_BLOCKS, 256, 0, stream>>>(Ab, Xb, Wc1, b1, nullptr, nullptr, 0, Ab);
    hipMemsetAsync(colsum, 0, sizeof(float) * 256, stream);
    k_colstats_bf<<<304, 256, 0, stream>>>(Ab, colsum, colsumsq);
    k_bnfin<<<1, 128, 0, stream>>>(colsum, colsumsq, g1, be1, scaleS, shiftS);  // BN1

    // ---- layer 2 ----  (consumers apply BN1+ReLU on the fly; h2 PRE-BN in Bb)
    k_agg_bf<<<AGG_BLOCKS, 256, 0, stream>>>(Ab, rowstart, csr, Bb, scaleS, shiftS, 1);
    k_gemm_mfma<<<GEMM_BLOCKS, 256, 0, stream>>>(Bb, Ab, Wc2, b2, scaleS, shiftS, 1, Bb);
    hipMemsetAsync(colsum, 0, sizeof(float) * 256, stream);
    k_colstats_bf<<<304, 256, 0, stream>>>(Bb, colsum, colsumsq);
    k_bnfin<<<1, 128, 0, stream>>>(colsum, colsumsq, g2, be2, scaleS, shiftS);  // BN2

    // ---- layer 3 ----  (consumers apply BN2+ReLU; bias + log_softmax fused)
    k_agg_bf<<<AGG_BLOCKS, 256, 0, stream>>>(Bb, rowstart, csr, Ab, scaleS, shiftS, 1);
    k_gemm40_mfma<<<GEMM_BLOCKS, 256, 0, stream>>>(Ab, Bb, Wc3, b3, scaleS, shiftS, out);
}

// Round 6
// 512.768 us; speedup vs baseline: 1.1726x; 1.1726x over previous
//
#include <hip/hip_runtime.h>
#include <cstdint>
#include <cstddef>
#include <math.h>

#define N_NODES 100000
#define N_EDGES 1600000
#define DIM 128
#define DOUT 40
#define BN_EPS 1e-5f

// bucketed CSR build
#define NB 250          // buckets
#define NPB 400         // nodes per bucket (250*400 = 100000 exactly)
#define BCAP 8192       // bucket capacity (mean 6400, sigma ~80 -> 22 sigma headroom)

typedef __attribute__((ext_vector_type(8))) short bf16x8;
typedef __attribute__((ext_vector_type(4))) float f32x4;

__device__ __forceinline__ float bf2f(uint u16shifted) {
    union { uint i; float f; } c; c.i = u16shifted; return c.f;
}
__device__ __forceinline__ ushort f2bf(float f) {
    union { float f; uint i; } c; c.f = f;
    uint i = c.i;
    uint lsb = (i >> 16) & 1u;
    i += 0x7FFFu + lsb;
    return (ushort)(i >> 16);
}
// apply BN+ReLU to a packed pair of bf16 given per-col scale/shift, repack
__device__ __forceinline__ uint bnpack(uint u, float s0, float h0, float s1, float h1) {
    float lo = fmaxf(bf2f(u << 16) * s0 + h0, 0.f);
    float hi = fmaxf(bf2f(u & 0xFFFF0000u) * s1 + h1, 0.f);
    return (uint)f2bf(lo) | ((uint)f2bf(hi) << 16);
}

// ---------------- convert x -> bf16 ----------------
__global__ __launch_bounds__(256) void k_cvt(const float* __restrict__ in,
                                             ushort* __restrict__ out, int n4) {
    int i = blockIdx.x * blockDim.x + threadIdx.x;
    int stride = gridDim.x * blockDim.x;
    for (; i < n4; i += stride) {
        float4 v = reinterpret_cast<const float4*>(in)[i];
        ushort4 o;
        o.x = f2bf(v.x); o.y = f2bf(v.y); o.z = f2bf(v.z); o.w = f2bf(v.w);
        reinterpret_cast<ushort4*>(out)[i] = o;
    }
}

// ---------------- build Wcat[n][k] = k<128 ? W[k][n] : R[k-128][n], bf16, zero-pad n>=NW ----
__global__ void k_wcat(const float* __restrict__ W, const float* __restrict__ R,
                       ushort* __restrict__ out, int NW) {
    int idx = blockIdx.x * 256 + threadIdx.x;  // grid = Nout blocks
    int n = idx >> 8, k = idx & 255;
    float v = 0.f;
    if (n < NW) v = (k < 128) ? W[k * NW + n] : R[(k - 128) * NW + n];
    out[idx] = f2bf(v);
}

// ---------------- CSR pass A: partition edges into dst-buckets ----------------
// 256 blocks x 6250 edges; packed entry = (dloc << 17) | src  (dloc<400, src<2^17)
__global__ __launch_bounds__(256) void k_bucket(const int* __restrict__ ei,
                                                uint* __restrict__ bucketbuf,
                                                int* __restrict__ gcnt) {
    __shared__ int hist[NB];
    __shared__ int base_[NB];
    int tid = threadIdx.x;
    for (int i = tid; i < NB; i += 256) hist[i] = 0;
    __syncthreads();
    const int EPB = N_EDGES / 256;  // 6250
    int e0 = blockIdx.x * EPB, e1 = e0 + EPB;
    for (int e = e0 + tid; e < e1; e += 256) {
        int d = ei[N_EDGES + e];
        atomicAdd(&hist[d / NPB], 1);
    }
    __syncthreads();
    for (int i = tid; i < NB; i += 256) base_[i] = atomicAdd(&gcnt[i], hist[i]);
    __syncthreads();
    for (int i = tid; i < NB; i += 256) hist[i] = 0;
    __syncthreads();
    for (int e = e0 + tid; e < e1; e += 256) {
        int d = ei[N_EDGES + e];
        int s = ei[e];
        int b = d / NPB;
        int pos = base_[b] + atomicAdd(&hist[b], 1);
        if (pos < BCAP)
            bucketbuf[(size_t)b * BCAP + pos] = ((uint)(d - b * NPB) << 17) | (uint)s;
    }
}

__global__ void k_bscan(const int* __restrict__ gcnt, int* __restrict__ bbase) {
    if (threadIdx.x == 0) {
        int run = 0;
        for (int b = 0; b < NB; b++) { bbase[b] = run; run += gcnt[b]; }
        bbase[NB] = run;
    }
}

// ---------------- CSR pass B: per-bucket CSR entirely in LDS, stream out ----------------
__global__ __launch_bounds__(256) void k_csr_build(const int* __restrict__ ei,
                                                   const uint* __restrict__ bucketbuf,
                                                   const int* __restrict__ gcnt,
                                                   const int* __restrict__ bbase,
                                                   int* __restrict__ rowstart,
                                                   int* __restrict__ csr) {
    __shared__ int cnts[NPB + 1];
    __shared__ int lcur[NPB];
    __shared__ int csr_l[BCAP];
    int b = blockIdx.x, tid = threadIdx.x;
    int cnt = gcnt[b];
    int base = bbase[b];
    int lo = b * NPB;
    bool fits = (cnt <= BCAP);
    for (int i = tid; i < NPB; i += 256) cnts[i] = 0;
    __syncthreads();
    if (fits) {
        for (int i = tid; i < cnt; i += 256)
            atomicAdd(&cnts[bucketbuf[(size_t)b * BCAP + i] >> 17], 1);
    } else {  // overflow fallback (statistically never): full edge sweep
        for (int e = tid; e < N_EDGES; e += 256) {
            int d = ei[N_EDGES + e];
            if (d >= lo && d < lo + NPB) atomicAdd(&cnts[d - lo], 1);
        }
    }
    __syncthreads();
    if (tid == 0) {
        int run = 0;
        for (int i = 0; i < NPB; i++) { int c = cnts[i]; cnts[i] = run; run += c; }
        cnts[NPB] = run;
    }
    __syncthreads();
    for (int i = tid; i < NPB; i += 256) rowstart[lo + i] = base + cnts[i];
    if (b == NB - 1 && tid == 0) rowstart[N_NODES] = base + cnts[NPB];
    for (int i = tid; i < NPB; i += 256) lcur[i] = 0;
    __syncthreads();
    if (fits) {
        for (int i = tid; i < cnt; i += 256) {
            uint p = bucketbuf[(size_t)b * BCAP + i];
            int dl = p >> 17;
            int pos = cnts[dl] + atomicAdd(&lcur[dl], 1);
            csr_l[pos] = (int)(p & 0x1FFFFu);
        }
        __syncthreads();
        for (int i = tid; i < cnt; i += 256) csr[base + i] = csr_l[i];
    } else {
        for (int e = tid; e < N_EDGES; e += 256) {
            int d = ei[N_EDGES + e];
            if (d >= lo && d < lo + NPB) {
                int dl = d - lo;
                int pos = cnts[dl] + atomicAdd(&lcur[dl], 1);
                csr[base + pos] = ei[e];
            }
        }
    }
}

// ---------------- mean aggregation, bf16, 4 edges in flight, optional fused BN+ReLU --------
// one wave per node; lane = slot(0..3) x colgroup(0..15); each lane loads uint4 = 8 bf16 cols
__global__ __launch_bounds__(256) void k_agg_bf(const ushort* __restrict__ cur,
                                                const int* __restrict__ rowstart,
                                                const int* __restrict__ csr,
                                                ushort* __restrict__ out,
                                                const float* __restrict__ scale,
                                                const float* __restrict__ shift,
                                                int hasbn) {
    int wid = (blockIdx.x * blockDim.x + threadIdx.x) >> 6;
    int lane = threadIdx.x & 63;
    if (wid >= N_NODES) return;
    int beg = rowstart[wid];
    int end = rowstart[wid + 1];
    int slot = lane >> 4;   // which edge within a group of 4
    int cg = lane & 15;     // column group: cols cg*8 .. cg*8+7
    float sc0 = 1.f, sc1 = 1.f, sc2 = 1.f, sc3 = 1.f, sc4 = 1.f, sc5 = 1.f, sc6 = 1.f, sc7 = 1.f;
    float sh0 = 0.f, sh1 = 0.f, sh2 = 0.f, sh3 = 0.f, sh4 = 0.f, sh5 = 0.f, sh6 = 0.f, sh7 = 0.f;
    if (hasbn) {
        int c0 = cg * 8;
        sc0 = scale[c0 + 0]; sc1 = scale[c0 + 1]; sc2 = scale[c0 + 2]; sc3 = scale[c0 + 3];
        sc4 = scale[c0 + 4]; sc5 = scale[c0 + 5]; sc6 = scale[c0 + 6]; sc7 = scale[c0 + 7];
        sh0 = shift[c0 + 0]; sh1 = shift[c0 + 1]; sh2 = shift[c0 + 2]; sh3 = shift[c0 + 3];
        sh4 = shift[c0 + 4]; sh5 = shift[c0 + 5]; sh6 = shift[c0 + 6]; sh7 = shift[c0 + 7];
    }
    const uint4* base = reinterpret_cast<const uint4*>(cur);  // row = 16 x uint4
    float a0 = 0.f, a1 = 0.f, a2 = 0.f, a3 = 0.f, a4 = 0.f, a5 = 0.f, a6 = 0.f, a7 = 0.f;
#pragma unroll 2
    for (int e = beg + slot; e < end; e += 4) {
        int s = csr[e];
        uint4 u = base[(size_t)s * 16 + cg];
        float v0 = bf2f(u.x << 16), v1 = bf2f(u.x & 0xFFFF0000u);
        float v2 = bf2f(u.y << 16), v3 = bf2f(u.y & 0xFFFF0000u);
        float v4 = bf2f(u.z << 16), v5 = bf2f(u.z & 0xFFFF0000u);
        float v6 = bf2f(u.w << 16), v7 = bf2f(u.w & 0xFFFF0000u);
        if (hasbn) {
            v0 = fmaxf(v0 * sc0 + sh0, 0.f); v1 = fmaxf(v1 * sc1 + sh1, 0.f);
            v2 = fmaxf(v2 * sc2 + sh2, 0.f); v3 = fmaxf(v3 * sc3 + sh3, 0.f);
            v4 = fmaxf(v4 * sc4 + sh4, 0.f); v5 = fmaxf(v5 * sc5 + sh5, 0.f);
            v6 = fmaxf(v6 * sc6 + sh6, 0.f); v7 = fmaxf(v7 * sc7 + sh7, 0.f);
        }
        a0 += v0; a1 += v1; a2 += v2; a3 += v3;
        a4 += v4; a5 += v5; a6 += v6; a7 += v7;
    }
    // combine the 4 slots: lanes l, l^16, l^32
#pragma unroll
    for (int off = 16; off < 64; off <<= 1) {
        a0 += __shfl_xor(a0, off, 64); a1 += __shfl_xor(a1, off, 64);
        a2 += __shfl_xor(a2, off, 64); a3 += __shfl_xor(a3, off, 64);
        a4 += __shfl_xor(a4, off, 64); a5 += __shfl_xor(a5, off, 64);
        a6 += __shfl_xor(a6, off, 64); a7 += __shfl_xor(a7, off, 64);
    }
    if (slot == 0) {
        int deg = end - beg;
        float inv = 1.0f / (float)(deg > 1 ? deg : 1);
        uint4 o;
        o.x = (uint)f2bf(a0 * inv) | ((uint)f2bf(a1 * inv) << 16);
        o.y = (uint)f2bf(a2 * inv) | ((uint)f2bf(a3 * inv) << 16);
        o.z = (uint)f2bf(a4 * inv) | ((uint)f2bf(a5 * inv) << 16);
        o.w = (uint)f2bf(a6 * inv) | ((uint)f2bf(a7 * inv) << 16);
        reinterpret_cast<uint4*>(out)[(size_t)wid * 16 + cg] = o;
    }
}

// ---------------- MFMA GEMM: out[M,128] = mean@W + bnrelu(cur)@R + b ------------------------
// 128x128 tile, 256 threads = 4 waves as 2x2, each wave 64x64 (4x4 frags of 16x16x32)
// in-place safe for out==mean; Ac tile gets optional BN+ReLU applied at staging (scale/shift in LDS)
__global__ __launch_bounds__(256) void k_gemm_mfma(const ushort* __restrict__ Am,
                                                   const ushort* __restrict__ Ac,
                                                   const ushort* __restrict__ Wcat, // [128][256]
                                                   const float* __restrict__ bias,
                                                   const float* __restrict__ scale,
                                                   const float* __restrict__ shift,
                                                   int hasbn,
                                                   ushort* __restrict__ out) {
    __shared__ ushort As[128 * 40];  // 128 rows x 32 k, padded stride 40 (80 B)
    __shared__ ushort Bs[128 * 40];  // 128 cols x 32 k
    __shared__ float scS[128], shS[128];
    int tid = threadIdx.x;
    int wid = tid >> 6, lane = tid & 63;
    int wr = wid >> 1, wc = wid & 1;
    int l15 = lane & 15, lhi = lane >> 4;
    int row0 = blockIdx.x * 128;

    if (hasbn && tid < 128) { scS[tid] = scale[tid]; shS[tid] = shift[tid]; }

    f32x4 acc[4][4];
#pragma unroll
    for (int m = 0; m < 4; m++)
#pragma unroll
        for (int n = 0; n < 4; n++) acc[m][n] = (f32x4){0.f, 0.f, 0.f, 0.f};

    for (int ks = 0; ks < 8; ++ks) {
        int kg = ks * 32;
        bool self = (kg >= 128);
        const ushort* Asrc = self ? Ac : Am;
        int ka = kg & 127;
        bool doBN = self && hasbn;
        __syncthreads();
#pragma unroll
        for (int h = 0; h < 2; ++h) {
            int c = tid + h * 256;
            int row = c >> 2, q = c & 3;
            int gr = row0 + row;
            uint4 v = {0, 0, 0, 0};
            if (gr < N_NODES)
                v = *reinterpret_cast<const uint4*>(Asrc + (size_t)gr * 128 + ka + q * 8);
            if (doBN) {
                int cc = ka + q * 8;
                v.x = bnpack(v.x, scS[cc + 0], shS[cc + 0], scS[cc + 1], shS[cc + 1]);
                v.y = bnpack(v.y, scS[cc + 2], shS[cc + 2], scS[cc + 3], shS[cc + 3]);
                v.z = bnpack(v.z, scS[cc + 4], shS[cc + 4], scS[cc + 5], shS[cc + 5]);
                v.w = bnpack(v.w, scS[cc + 6], shS[cc + 6], scS[cc + 7], shS[cc + 7]);
            }
            *reinterpret_cast<uint4*>(&As[row * 40 + q * 8]) = v;
        }
#pragma unroll
        for (int h = 0; h < 2; ++h) {
            int c = tid + h * 256;
            int n = c >> 2, q = c & 3;
            *reinterpret_cast<uint4*>(&Bs[n * 40 + q * 8]) =
                *reinterpret_cast<const uint4*>(Wcat + n * 256 + kg + q * 8);
        }
        __syncthreads();
        bf16x8 a[4], b[4];
#pragma unroll
        for (int m = 0; m < 4; m++)
            a[m] = *reinterpret_cast<bf16x8*>(&As[(wr * 64 + m * 16 + l15) * 40 + lhi * 8]);
#pragma unroll
        for (int n = 0; n < 4; n++)
            b[n] = *reinterpret_cast<bf16x8*>(&Bs[(wc * 64 + n * 16 + l15) * 40 + lhi * 8]);
#pragma unroll
        for (int m = 0; m < 4; m++)
#pragma unroll
            for (int n = 0; n < 4; n++)
                acc[m][n] = __builtin_amdgcn_mfma_f32_16x16x32_bf16(a[m], b[n], acc[m][n], 0, 0, 0);
    }
    // epilogue: + bias, bf16 store
#pragma unroll
    for (int m = 0; m < 4; m++) {
        int rbase = row0 + wr * 64 + m * 16 + lhi * 4;
#pragma unroll
        for (int n = 0; n < 4; n++) {
            int col = wc * 64 + n * 16 + l15;
            float bv = bias[col];
#pragma unroll
            for (int j = 0; j < 4; j++) {
                int gr = rbase + j;
                if (gr < N_NODES) out[(size_t)gr * 128 + col] = f2bf(acc[m][n][j] + bv);
            }
        }
    }
}

// ---------------- layer-3 MFMA GEMM + bias + log_softmax fused ----------------
// 128 rows x 48 cols (40 padded to 48); 4 waves, wave w: rows w*32..+31 (2 frags), 3 col frags
__global__ __launch_bounds__(256) void k_gemm40_mfma(const ushort* __restrict__ Am,
                                                     const ushort* __restrict__ Ac,
                                                     const ushort* __restrict__ Wcat, // [48][256]
                                                     const float* __restrict__ bias,  // [40]
                                                     const float* __restrict__ scale,
                                                     const float* __restrict__ shift,
                                                     float* __restrict__ out) {
    __shared__ ushort As[128 * 40];
    __shared__ ushort Bs[48 * 40];
    __shared__ float scS[128], shS[128];
    int tid = threadIdx.x;
    int w = tid >> 6, lane = tid & 63;
    int l15 = lane & 15, lhi = lane >> 4;
    int row0 = blockIdx.x * 128;

    if (tid < 128) { scS[tid] = scale[tid]; shS[tid] = shift[tid]; }

    f32x4 acc[2][3];
#pragma unroll
    for (int m = 0; m < 2; m++)
#pragma unroll
        for (int n = 0; n < 3; n++) acc[m][n] = (f32x4){0.f, 0.f, 0.f, 0.f};

    for (int ks = 0; ks < 8; ++ks) {
        int kg = ks * 32;
        bool self = (kg >= 128);
        const ushort* Asrc = self ? Ac : Am;
        int ka = kg & 127;
        __syncthreads();
#pragma unroll
        for (int h = 0; h < 2; ++h) {
            int c = tid + h * 256;
            int row = c >> 2, q = c & 3;
            int gr = row0 + row;
            uint4 v = {0, 0, 0, 0};
            if (gr < N_NODES)
                v = *reinterpret_cast<const uint4*>(Asrc + (size_t)gr * 128 + ka + q * 8);
            if (self) {
                int cc = ka + q * 8;
                v.x = bnpack(v.x, scS[cc + 0], shS[cc + 0], scS[cc + 1], shS[cc + 1]);
                v.y = bnpack(v.y, scS[cc + 2], shS[cc + 2], scS[cc + 3], shS[cc + 3]);
                v.z = bnpack(v.z, scS[cc + 4], shS[cc + 4], scS[cc + 5], shS[cc + 5]);
                v.w = bnpack(v.w, scS[cc + 6], shS[cc + 6], scS[cc + 7], shS[cc + 7]);
            }
            *reinterpret_cast<uint4*>(&As[row * 40 + q * 8]) = v;
        }
        if (tid < 192) {
            int n = tid >> 2, q = tid & 3;
            *reinterpret_cast<uint4*>(&Bs[n * 40 + q * 8]) =
                *reinterpret_cast<const uint4*>(Wcat + n * 256 + kg + q * 8);
        }
        __syncthreads();
        bf16x8 a[2], b[3];
#pragma unroll
        for (int m = 0; m < 2; m++)
            a[m] = *reinterpret_cast<bf16x8*>(&As[(w * 32 + m * 16 + l15) * 40 + lhi * 8]);
#pragma unroll
        for (int n = 0; n < 3; n++)
            b[n] = *reinterpret_cast<bf16x8*>(&Bs[(n * 16 + l15) * 40 + lhi * 8]);
#pragma unroll
        for (int m = 0; m < 2; m++)
#pragma unroll
            for (int n = 0; n < 3; n++)
                acc[m][n] = __builtin_amdgcn_mfma_f32_16x16x32_bf16(a[m], b[n], acc[m][n], 0, 0, 0);
    }
    // epilogue: bias + log_softmax per row (row lives in a 16-lane group)
    float b0 = bias[l15];
    float b1 = bias[16 + l15];
    float b2 = (l15 < 8) ? bias[32 + l15] : 0.f;
#pragma unroll
    for (int m = 0; m < 2; m++) {
#pragma unroll
        for (int j = 0; j < 4; j++) {
            int grow = row0 + w * 32 + m * 16 + lhi * 4 + j;
            float v0 = acc[m][0][j] + b0;
            float v1 = acc[m][1][j] + b1;
            float v2 = (l15 < 8) ? (acc[m][2][j] + b2) : -INFINITY;
            float mx = fmaxf(fmaxf(v0, v1), v2);
#pragma unroll
            for (int off = 1; off < 16; off <<= 1) mx = fmaxf(mx, __shfl_xor(mx, off, 64));
            float s = expf(v0 - mx) + expf(v1 - mx) + ((l15 < 8) ? expf(v2 - mx) : 0.f);
#pragma unroll
            for (int off = 1; off < 16; off <<= 1) s += __shfl_xor(s, off, 64);
            float lg = mx + logf(s);
            if (grow < N_NODES) {
                out[(size_t)grow * DOUT + l15] = v0 - lg;
                out[(size_t)grow * DOUT + 16 + l15] = v1 - lg;
                if (l15 < 8) out[(size_t)grow * DOUT + 32 + l15] = v2 - lg;
            }
        }
    }
}

// ---------------- BN stats on bf16 H (pre-BN) ----------------
__global__ __launch_bounds__(256) void k_colstats_bf(const ushort* __restrict__ H,
                                                     float* __restrict__ sum,
                                                     float* __restrict__ sumsq) {
    int tid = threadIdx.x;
    int cg = tid & 31;   // cols cg*4..cg*4+3
    int rr = tid >> 5;   // 0..7
    float s[4] = {0, 0, 0, 0}, s2[4] = {0, 0, 0, 0};
    for (int r = blockIdx.x * 8 + rr; r < N_NODES; r += gridDim.x * 8) {
        uint2 u = *reinterpret_cast<const uint2*>(H + (size_t)r * 128 + cg * 4);
        float f0 = bf2f(u.x << 16), f1 = bf2f(u.x & 0xFFFF0000u);
        float f2 = bf2f(u.y << 16), f3 = bf2f(u.y & 0xFFFF0000u);
        s[0] += f0; s2[0] += f0 * f0;
        s[1] += f1; s2[1] += f1 * f1;
        s[2] += f2; s2[2] += f2 * f2;
        s[3] += f3; s2[3] += f3 * f3;
    }
    __shared__ float ls[256][4], ls2[256][4];
#pragma unroll
    for (int i = 0; i < 4; i++) { ls[tid][i] = s[i]; ls2[tid][i] = s2[i]; }
    __syncthreads();
    if (tid < 32) {
#pragma unroll
        for (int j = 1; j < 8; j++)
#pragma unroll
            for (int i = 0; i < 4; i++) { s[i] += ls[j * 32 + tid][i]; s2[i] += ls2[j * 32 + tid][i]; }
#pragma unroll
        for (int i = 0; i < 4; i++) {
            atomicAdd(&sum[tid * 4 + i], s[i]);
            atomicAdd(&sumsq[tid * 4 + i], s2[i]);
        }
    }
}

__global__ void k_bnfin(const float* __restrict__ sum, const float* __restrict__ sumsq,
                        const float* __restrict__ g, const float* __restrict__ be,
                        float* __restrict__ scale, float* __restrict__ shift) {
    int c = threadIdx.x;
    if (c < DIM) {
        float mu = sum[c] * (1.0f / N_NODES);
        float var = sumsq[c] * (1.0f / N_NODES) - mu * mu;
        float sc = g[c] * rsqrtf(var + BN_EPS);
        scale[c] = sc;
        shift[c] = be[c] - mu * sc;
    }
}

// ---------------- launch ----------------
extern "C" void kernel_launch(void* const* d_in, const int* in_sizes, int n_in,
                              void* d_out, int out_size, void* d_ws, size_t ws_size,
                              hipStream_t stream) {
    const float* x = (const float*)d_in[0];
    const int* ei = (const int*)d_in[1];
    const float* w1 = (const float*)d_in[2];
    const float* r1 = (const float*)d_in[3];
    const float* b1 = (const float*)d_in[4];
    const float* g1 = (const float*)d_in[5];
    const float* be1 = (const float*)d_in[6];
    const float* w2 = (const float*)d_in[7];
    const float* r2 = (const float*)d_in[8];
    const float* b2 = (const float*)d_in[9];
    const float* g2 = (const float*)d_in[10];
    const float* be2 = (const float*)d_in[11];
    const float* w3 = (const float*)d_in[12];
    const float* r3 = (const float*)d_in[13];
    const float* b3 = (const float*)d_in[14];
    float* out = (float*)d_out;

    const size_t NF = (size_t)N_NODES * DIM;  // 12.8M
    ushort* Xb = (ushort*)d_ws;
    ushort* Ab = Xb + NF;
    ushort* Bb = Ab + NF;
    ushort* Wc1 = Bb + NF;             // 128*256
    ushort* Wc2 = Wc1 + 128 * 256;
    ushort* Wc3 = Wc2 + 128 * 256;     // 48*256
    uint* bucketbuf = (uint*)(Wc3 + 48 * 256);   // NB*BCAP = 2.048M uints
    int* gcnt = (int*)(bucketbuf + (size_t)NB * BCAP);  // NB
    int* bbase = gcnt + NB;                       // NB+1
    int* rowstart = bbase + NB + 1;               // N+1
    int* csr = rowstart + (N_NODES + 1);          // E
    float* colsum = (float*)(csr + N_EDGES);      // 128
    float* colsumsq = colsum + 128;
    float* scaleS = colsumsq + 128;
    float* shiftS = scaleS + 128;
    size_t needed = (size_t)((char*)(shiftS + 128) - (char*)d_ws);
    if (ws_size < needed) return;

    const int AGG_BLOCKS = N_NODES / 4;               // 25000
    const int GEMM_BLOCKS = (N_NODES + 127) / 128;    // 782

    // conversions
    k_cvt<<<2048, 256, 0, stream>>>(x, Xb, (int)(NF / 4));
    k_wcat<<<128, 256, 0, stream>>>(w1, r1, Wc1, 128);
    k_wcat<<<128, 256, 0, stream>>>(w2, r2, Wc2, 128);
    k_wcat<<<48, 256, 0, stream>>>(w3, r3, Wc3, DOUT);

    // CSR build (bucketed, 2-pass)
    hipMemsetAsync(gcnt, 0, sizeof(int) * NB, stream);
    k_bucket<<<256, 256, 0, stream>>>(ei, bucketbuf, gcnt);
    k_bscan<<<1, 64, 0, stream>>>(gcnt, bbase);
    k_csr_build<<<NB, 256, 0, stream>>>(ei, bucketbuf, gcnt, bbase, rowstart, csr);

    // ---- layer 1 ----  (h1 = gemm output, PRE-BN, stored in Ab)
    k_agg_bf<<<AGG_BLOCKS, 256, 0, stream>>>(Xb, rowstart, csr, Ab, nullptr, nullptr, 0);
    k_gemm_mfma<<<GEMM_BLOCKS, 256, 0, stream>>>(Ab, Xb, Wc1, b1, nullptr, nullptr, 0, Ab);
    hipMemsetAsync(colsum, 0, sizeof(float) * 256, stream);
    k_colstats_bf<<<304, 256, 0, stream>>>(Ab, colsum, colsumsq);
    k_bnfin<<<1, 128, 0, stream>>>(colsum, colsumsq, g1, be1, scaleS, shiftS);  // BN1

    // ---- layer 2 ----  (consumers apply BN1+ReLU on the fly; h2 PRE-BN in Bb)
    k_agg_bf<<<AGG_BLOCKS, 256, 0, stream>>>(Ab, rowstart, csr, Bb, scaleS, shiftS, 1);
    k_gemm_mfma<<<GEMM_BLOCKS, 256, 0, stream>>>(Bb, Ab, Wc2, b2, scaleS, shiftS, 1, Bb);
    hipMemsetAsync(colsum, 0, sizeof(float) * 256, stream);
    k_colstats_bf<<<304, 256, 0, stream>>>(Bb, colsum, colsumsq);
    k_bnfin<<<1, 128, 0, stream>>>(colsum, colsumsq, g2, be2, scaleS, shiftS);  // BN2

    // ---- layer 3 ----  (consumers apply BN2+ReLU; bias + log_softmax fused)
    k_agg_bf<<<AGG_BLOCKS, 256, 0, stream>>>(Bb, rowstart, csr, Ab, scaleS, shiftS, 1);
    k_gemm40_mfma<<<GEMM_BLOCKS, 256, 0, stream>>>(Ab, Bb, Wc3, b3, scaleS, shiftS, out);
}

// Round 7
// 466.226 us; speedup vs baseline: 1.2897x; 1.0998x over previous
//
#include <hip/hip_runtime.h>
#include <cstdint>
#include <cstddef>
#include <math.h>

#define N_NODES 100000
#define N_EDGES 1600000
#define DIM 128
#define DOUT 40
#define BN_EPS 1e-5f

// bucketed CSR build
#define NB 250          // buckets
#define NPB 400         // nodes per bucket (250*400 = 100000 exactly)
#define BCAP 8192       // bucket capacity (mean 6400 -> huge headroom)

typedef __attribute__((ext_vector_type(8))) short bf16x8;
typedef __attribute__((ext_vector_type(4))) float f32x4;

__device__ __forceinline__ float bf2f(uint u16shifted) {
    union { uint i; float f; } c; c.i = u16shifted; return c.f;
}
__device__ __forceinline__ ushort f2bf(float f) {
    union { float f; uint i; } c; c.f = f;
    uint i = c.i;
    uint lsb = (i >> 16) & 1u;
    i += 0x7FFFu + lsb;
    return (ushort)(i >> 16);
}
// apply BN+ReLU to a packed pair of bf16 given per-col scale/shift, repack
__device__ __forceinline__ uint bnpack(uint u, float s0, float h0, float s1, float h1) {
    float lo = fmaxf(bf2f(u << 16) * s0 + h0, 0.f);
    float hi = fmaxf(bf2f(u & 0xFFFF0000u) * s1 + h1, 0.f);
    return (uint)f2bf(lo) | ((uint)f2bf(hi) << 16);
}

// ---------------- convert x -> bf16 ----------------
__global__ __launch_bounds__(256) void k_cvt(const float* __restrict__ in,
                                             ushort* __restrict__ out, int n4) {
    int i = blockIdx.x * blockDim.x + threadIdx.x;
    int stride = gridDim.x * blockDim.x;
    for (; i < n4; i += stride) {
        float4 v = reinterpret_cast<const float4*>(in)[i];
        ushort4 o;
        o.x = f2bf(v.x); o.y = f2bf(v.y); o.z = f2bf(v.z); o.w = f2bf(v.w);
        reinterpret_cast<ushort4*>(out)[i] = o;
    }
}

// ---------------- build Wcat[n][k] = k<128 ? W[k][n] : R[k-128][n], bf16, zero-pad n>=NW ----
__global__ void k_wcat(const float* __restrict__ W, const float* __restrict__ R,
                       ushort* __restrict__ out, int NW) {
    int idx = blockIdx.x * 256 + threadIdx.x;  // grid = Nout blocks
    int n = idx >> 8, k = idx & 255;
    float v = 0.f;
    if (n < NW) v = (k < 128) ? W[k * NW + n] : R[(k - 128) * NW + n];
    out[idx] = f2bf(v);
}

// ---------------- CSR pass A: partition edges into dst-buckets ----------------
__global__ __launch_bounds__(256) void k_bucket(const int* __restrict__ ei,
                                                uint* __restrict__ bucketbuf,
                                                int* __restrict__ gcnt) {
    __shared__ int hist[NB];
    __shared__ int base_[NB];
    int tid = threadIdx.x;
    for (int i = tid; i < NB; i += 256) hist[i] = 0;
    __syncthreads();
    const int EPB = N_EDGES / 256;  // 6250
    int e0 = blockIdx.x * EPB, e1 = e0 + EPB;
    for (int e = e0 + tid; e < e1; e += 256) {
        int d = ei[N_EDGES + e];
        atomicAdd(&hist[d / NPB], 1);
    }
    __syncthreads();
    for (int i = tid; i < NB; i += 256) base_[i] = atomicAdd(&gcnt[i], hist[i]);
    __syncthreads();
    for (int i = tid; i < NB; i += 256) hist[i] = 0;
    __syncthreads();
    for (int e = e0 + tid; e < e1; e += 256) {
        int d = ei[N_EDGES + e];
        int s = ei[e];
        int b = d / NPB;
        int pos = base_[b] + atomicAdd(&hist[b], 1);
        if (pos < BCAP)
            bucketbuf[(size_t)b * BCAP + pos] = ((uint)(d - b * NPB) << 17) | (uint)s;
    }
}

__global__ void k_bscan(const int* __restrict__ gcnt, int* __restrict__ bbase) {
    if (threadIdx.x == 0) {
        int run = 0;
        for (int b = 0; b < NB; b++) { bbase[b] = run; run += gcnt[b]; }
        bbase[NB] = run;
    }
}

// ---------------- CSR pass B: per-bucket CSR entirely in LDS, stream out ----------------
__global__ __launch_bounds__(256) void k_csr_build(const int* __restrict__ ei,
                                                   const uint* __restrict__ bucketbuf,
                                                   const int* __restrict__ gcnt,
                                                   const int* __restrict__ bbase,
                                                   int* __restrict__ rowstart,
                                                   int* __restrict__ csr) {
    __shared__ int cnts[NPB + 1];
    __shared__ int lcur[NPB];
    __shared__ int csr_l[BCAP];
    int b = blockIdx.x, tid = threadIdx.x;
    int cnt = gcnt[b];
    int base = bbase[b];
    int lo = b * NPB;
    bool fits = (cnt <= BCAP);
    for (int i = tid; i < NPB; i += 256) cnts[i] = 0;
    __syncthreads();
    if (fits) {
        for (int i = tid; i < cnt; i += 256)
            atomicAdd(&cnts[bucketbuf[(size_t)b * BCAP + i] >> 17], 1);
    } else {  // overflow fallback (statistically never): full edge sweep
        for (int e = tid; e < N_EDGES; e += 256) {
            int d = ei[N_EDGES + e];
            if (d >= lo && d < lo + NPB) atomicAdd(&cnts[d - lo], 1);
        }
    }
    __syncthreads();
    if (tid == 0) {
        int run = 0;
        for (int i = 0; i < NPB; i++) { int c = cnts[i]; cnts[i] = run; run += c; }
        cnts[NPB] = run;
    }
    __syncthreads();
    for (int i = tid; i < NPB; i += 256) rowstart[lo + i] = base + cnts[i];
    if (b == NB - 1 && tid == 0) rowstart[N_NODES] = base + cnts[NPB];
    for (int i = tid; i < NPB; i += 256) lcur[i] = 0;
    __syncthreads();
    if (fits) {
        for (int i = tid; i < cnt; i += 256) {
            uint p = bucketbuf[(size_t)b * BCAP + i];
            int dl = p >> 17;
            int pos = cnts[dl] + atomicAdd(&lcur[dl], 1);
            csr_l[pos] = (int)(p & 0x1FFFFu);
        }
        __syncthreads();
        for (int i = tid; i < cnt; i += 256) csr[base + i] = csr_l[i];
    } else {
        for (int e = tid; e < N_EDGES; e += 256) {
            int d = ei[N_EDGES + e];
            if (d >= lo && d < lo + NPB) {
                int dl = d - lo;
                int pos = cnts[dl] + atomicAdd(&lcur[dl], 1);
                csr[base + pos] = ei[e];
            }
        }
    }
}

// ---------------- mean aggregation, bf16, 16 gathers in flight, optional fused BN+ReLU -----
// one wave per node; lane = slot(0..3) x colgroup(0..15); each lane loads uint4 = 8 bf16 cols
// main loop: 16 edges (4 per slot) with 4 independent csr loads + 4 independent gathers
__global__ __launch_bounds__(256) void k_agg_bf(const ushort* __restrict__ cur,
                                                const int* __restrict__ rowstart,
                                                const int* __restrict__ csr,
                                                ushort* __restrict__ out,
                                                const float* __restrict__ scale,
                                                const float* __restrict__ shift,
                                                int hasbn) {
    int wid = (blockIdx.x * blockDim.x + threadIdx.x) >> 6;
    int lane = threadIdx.x & 63;
    if (wid >= N_NODES) return;
    int beg = rowstart[wid];
    int end = rowstart[wid + 1];
    int slot = lane >> 4;   // which edge within a group of 4
    int cg = lane & 15;     // column group: cols cg*8 .. cg*8+7
    float sc0 = 1.f, sc1 = 1.f, sc2 = 1.f, sc3 = 1.f, sc4 = 1.f, sc5 = 1.f, sc6 = 1.f, sc7 = 1.f;
    float sh0 = 0.f, sh1 = 0.f, sh2 = 0.f, sh3 = 0.f, sh4 = 0.f, sh5 = 0.f, sh6 = 0.f, sh7 = 0.f;
    if (hasbn) {
        int c0 = cg * 8;
        sc0 = scale[c0 + 0]; sc1 = scale[c0 + 1]; sc2 = scale[c0 + 2]; sc3 = scale[c0 + 3];
        sc4 = scale[c0 + 4]; sc5 = scale[c0 + 5]; sc6 = scale[c0 + 6]; sc7 = scale[c0 + 7];
        sh0 = shift[c0 + 0]; sh1 = shift[c0 + 1]; sh2 = shift[c0 + 2]; sh3 = shift[c0 + 3];
        sh4 = shift[c0 + 4]; sh5 = shift[c0 + 5]; sh6 = shift[c0 + 6]; sh7 = shift[c0 + 7];
    }
    const uint4* base = reinterpret_cast<const uint4*>(cur);  // row = 16 x uint4
    float a0 = 0.f, a1 = 0.f, a2 = 0.f, a3 = 0.f, a4 = 0.f, a5 = 0.f, a6 = 0.f, a7 = 0.f;

#define ACCUM(u) do { \
        float v0 = bf2f((u).x << 16), v1 = bf2f((u).x & 0xFFFF0000u); \
        float v2 = bf2f((u).y << 16), v3 = bf2f((u).y & 0xFFFF0000u); \
        float v4 = bf2f((u).z << 16), v5 = bf2f((u).z & 0xFFFF0000u); \
        float v6 = bf2f((u).w << 16), v7 = bf2f((u).w & 0xFFFF0000u); \
        if (hasbn) { \
            v0 = fmaxf(v0 * sc0 + sh0, 0.f); v1 = fmaxf(v1 * sc1 + sh1, 0.f); \
            v2 = fmaxf(v2 * sc2 + sh2, 0.f); v3 = fmaxf(v3 * sc3 + sh3, 0.f); \
            v4 = fmaxf(v4 * sc4 + sh4, 0.f); v5 = fmaxf(v5 * sc5 + sh5, 0.f); \
            v6 = fmaxf(v6 * sc6 + sh6, 0.f); v7 = fmaxf(v7 * sc7 + sh7, 0.f); \
        } \
        a0 += v0; a1 += v1; a2 += v2; a3 += v3; \
        a4 += v4; a5 += v5; a6 += v6; a7 += v7; \
    } while (0)

    int e = beg + slot;
    // main: 16 edges per wave-iteration (4 per slot), 4 independent chains
    for (; e + 12 < end; e += 16) {
        int s0 = csr[e];
        int s1 = csr[e + 4];
        int s2 = csr[e + 8];
        int s3 = csr[e + 12];
        uint4 u0 = base[(size_t)s0 * 16 + cg];
        uint4 u1 = base[(size_t)s1 * 16 + cg];
        uint4 u2 = base[(size_t)s2 * 16 + cg];
        uint4 u3 = base[(size_t)s3 * 16 + cg];
        ACCUM(u0); ACCUM(u1); ACCUM(u2); ACCUM(u3);
    }
    // tail: 4 edges per iteration
    for (; e < end; e += 4) {
        int s = csr[e];
        uint4 u = base[(size_t)s * 16 + cg];
        ACCUM(u);
    }
#undef ACCUM

    // combine the 4 slots: lanes l, l^16, l^32
#pragma unroll
    for (int off = 16; off < 64; off <<= 1) {
        a0 += __shfl_xor(a0, off, 64); a1 += __shfl_xor(a1, off, 64);
        a2 += __shfl_xor(a2, off, 64); a3 += __shfl_xor(a3, off, 64);
        a4 += __shfl_xor(a4, off, 64); a5 += __shfl_xor(a5, off, 64);
        a6 += __shfl_xor(a6, off, 64); a7 += __shfl_xor(a7, off, 64);
    }
    if (slot == 0) {
        int deg = end - beg;
        float inv = 1.0f / (float)(deg > 1 ? deg : 1);
        uint4 o;
        o.x = (uint)f2bf(a0 * inv) | ((uint)f2bf(a1 * inv) << 16);
        o.y = (uint)f2bf(a2 * inv) | ((uint)f2bf(a3 * inv) << 16);
        o.z = (uint)f2bf(a4 * inv) | ((uint)f2bf(a5 * inv) << 16);
        o.w = (uint)f2bf(a6 * inv) | ((uint)f2bf(a7 * inv) << 16);
        reinterpret_cast<uint4*>(out)[(size_t)wid * 16 + cg] = o;
    }
}

// ---------------- MFMA GEMM: out[M,128] = mean@W + bnrelu(cur)@R + b, fused col-stats ------
// 128x128 tile, 256 threads = 4 waves as 2x2, each wave 64x64 (4x4 frags of 16x16x32)
// in-place safe for out==mean; Ac tile gets optional BN+ReLU applied at staging
__global__ __launch_bounds__(256) void k_gemm_mfma(const ushort* __restrict__ Am,
                                                   const ushort* __restrict__ Ac,
                                                   const ushort* __restrict__ Wcat, // [128][256]
                                                   const float* __restrict__ bias,
                                                   const float* __restrict__ scale,
                                                   const float* __restrict__ shift,
                                                   int hasbn,
                                                   ushort* __restrict__ out,
                                                   float* __restrict__ csum,
                                                   float* __restrict__ csumsq,
                                                   int dostats) {
    __shared__ ushort As[128 * 40];  // 128 rows x 32 k, padded stride 40 (80 B)
    __shared__ ushort Bs[128 * 40];  // 128 cols x 32 k
    __shared__ float scS[128], shS[128];
    __shared__ float lsum[128], lsumsq[128];
    int tid = threadIdx.x;
    int wid = tid >> 6, lane = tid & 63;
    int wr = wid >> 1, wc = wid & 1;
    int l15 = lane & 15, lhi = lane >> 4;
    int row0 = blockIdx.x * 128;

    if (hasbn && tid < 128) { scS[tid] = scale[tid]; shS[tid] = shift[tid]; }
    if (dostats && tid < 128) { lsum[tid] = 0.f; lsumsq[tid] = 0.f; }

    f32x4 acc[4][4];
#pragma unroll
    for (int m = 0; m < 4; m++)
#pragma unroll
        for (int n = 0; n < 4; n++) acc[m][n] = (f32x4){0.f, 0.f, 0.f, 0.f};

    for (int ks = 0; ks < 8; ++ks) {
        int kg = ks * 32;
        bool self = (kg >= 128);
        const ushort* Asrc = self ? Ac : Am;
        int ka = kg & 127;
        bool doBN = self && hasbn;
        __syncthreads();
#pragma unroll
        for (int h = 0; h < 2; ++h) {
            int c = tid + h * 256;
            int row = c >> 2, q = c & 3;
            int gr = row0 + row;
            uint4 v = {0, 0, 0, 0};
            if (gr < N_NODES)
                v = *reinterpret_cast<const uint4*>(Asrc + (size_t)gr * 128 + ka + q * 8);
            if (doBN) {
                int cc = ka + q * 8;
                v.x = bnpack(v.x, scS[cc + 0], shS[cc + 0], scS[cc + 1], shS[cc + 1]);
                v.y = bnpack(v.y, scS[cc + 2], shS[cc + 2], scS[cc + 3], shS[cc + 3]);
                v.z = bnpack(v.z, scS[cc + 4], shS[cc + 4], scS[cc + 5], shS[cc + 5]);
                v.w = bnpack(v.w, scS[cc + 6], shS[cc + 6], scS[cc + 7], shS[cc + 7]);
            }
            *reinterpret_cast<uint4*>(&As[row * 40 + q * 8]) = v;
        }
#pragma unroll
        for (int h = 0; h < 2; ++h) {
            int c = tid + h * 256;
            int n = c >> 2, q = c & 3;
            *reinterpret_cast<uint4*>(&Bs[n * 40 + q * 8]) =
                *reinterpret_cast<const uint4*>(Wcat + n * 256 + kg + q * 8);
        }
        __syncthreads();
        bf16x8 a[4], b[4];
#pragma unroll
        for (int m = 0; m < 4; m++)
            a[m] = *reinterpret_cast<bf16x8*>(&As[(wr * 64 + m * 16 + l15) * 40 + lhi * 8]);
#pragma unroll
        for (int n = 0; n < 4; n++)
            b[n] = *reinterpret_cast<bf16x8*>(&Bs[(wc * 64 + n * 16 + l15) * 40 + lhi * 8]);
#pragma unroll
        for (int m = 0; m < 4; m++)
#pragma unroll
            for (int n = 0; n < 4; n++)
                acc[m][n] = __builtin_amdgcn_mfma_f32_16x16x32_bf16(a[m], b[n], acc[m][n], 0, 0, 0);
    }
    // epilogue: + bias, bf16 store, per-column stats partials
    float ps[4] = {0.f, 0.f, 0.f, 0.f}, ps2[4] = {0.f, 0.f, 0.f, 0.f};
#pragma unroll
    for (int m = 0; m < 4; m++) {
        int rbase = row0 + wr * 64 + m * 16 + lhi * 4;
#pragma unroll
        for (int n = 0; n < 4; n++) {
            int col = wc * 64 + n * 16 + l15;
            float bv = bias[col];
#pragma unroll
            for (int j = 0; j < 4; j++) {
                int gr = rbase + j;
                if (gr < N_NODES) {
                    float v = acc[m][n][j] + bv;
                    out[(size_t)gr * 128 + col] = f2bf(v);
                    ps[n] += v;
                    ps2[n] += v * v;
                }
            }
        }
    }
    if (dostats) {
        // reduce over the 4 lhi groups (same col), then LDS, then global
#pragma unroll
        for (int n = 0; n < 4; n++) {
            ps[n] += __shfl_xor(ps[n], 16, 64);
            ps2[n] += __shfl_xor(ps2[n], 16, 64);
            ps[n] += __shfl_xor(ps[n], 32, 64);
            ps2[n] += __shfl_xor(ps2[n], 32, 64);
        }
        if (lhi == 0) {
#pragma unroll
            for (int n = 0; n < 4; n++) {
                int col = wc * 64 + n * 16 + l15;
                atomicAdd(&lsum[col], ps[n]);
                atomicAdd(&lsumsq[col], ps2[n]);
            }
        }
        __syncthreads();
        if (tid < 128) {
            atomicAdd(&csum[tid], lsum[tid]);
            atomicAdd(&csumsq[tid], lsumsq[tid]);
        }
    }
}

// ---------------- layer-3 MFMA GEMM + bias + log_softmax fused ----------------
// 128 rows x 48 cols (40 padded to 48); 4 waves, wave w: rows w*32..+31 (2 frags), 3 col frags
__global__ __launch_bounds__(256) void k_gemm40_mfma(const ushort* __restrict__ Am,
                                                     const ushort* __restrict__ Ac,
                                                     const ushort* __restrict__ Wcat, // [48][256]
                                                     const float* __restrict__ bias,  // [40]
                                                     const float* __restrict__ scale,
                                                     const float* __restrict__ shift,
                                                     float* __restrict__ out) {
    __shared__ ushort As[128 * 40];
    __shared__ ushort Bs[48 * 40];
    __shared__ float scS[128], shS[128];
    int tid = threadIdx.x;
    int w = tid >> 6, lane = tid & 63;
    int l15 = lane & 15, lhi = lane >> 4;
    int row0 = blockIdx.x * 128;

    if (tid < 128) { scS[tid] = scale[tid]; shS[tid] = shift[tid]; }

    f32x4 acc[2][3];
#pragma unroll
    for (int m = 0; m < 2; m++)
#pragma unroll
        for (int n = 0; n < 3; n++) acc[m][n] = (f32x4){0.f, 0.f, 0.f, 0.f};

    for (int ks = 0; ks < 8; ++ks) {
        int kg = ks * 32;
        bool self = (kg >= 128);
        const ushort* Asrc = self ? Ac : Am;
        int ka = kg & 127;
        __syncthreads();
#pragma unroll
        for (int h = 0; h < 2; ++h) {
            int c = tid + h * 256;
            int row = c >> 2, q = c & 3;
            int gr = row0 + row;
            uint4 v = {0, 0, 0, 0};
            if (gr < N_NODES)
                v = *reinterpret_cast<const uint4*>(Asrc + (size_t)gr * 128 + ka + q * 8);
            if (self) {
                int cc = ka + q * 8;
                v.x = bnpack(v.x, scS[cc + 0], shS[cc + 0], scS[cc + 1], shS[cc + 1]);
                v.y = bnpack(v.y, scS[cc + 2], shS[cc + 2], scS[cc + 3], shS[cc + 3]);
                v.z = bnpack(v.z, scS[cc + 4], shS[cc + 4], scS[cc + 5], shS[cc + 5]);
                v.w = bnpack(v.w, scS[cc + 6], shS[cc + 6], scS[cc + 7], shS[cc + 7]);
            }
            *reinterpret_cast<uint4*>(&As[row * 40 + q * 8]) = v;
        }
        if (tid < 192) {
            int n = tid >> 2, q = tid & 3;
            *reinterpret_cast<uint4*>(&Bs[n * 40 + q * 8]) =
                *reinterpret_cast<const uint4*>(Wcat + n * 256 + kg + q * 8);
        }
        __syncthreads();
        bf16x8 a[2], b[3];
#pragma unroll
        for (int m = 0; m < 2; m++)
            a[m] = *reinterpret_cast<bf16x8*>(&As[(w * 32 + m * 16 + l15) * 40 + lhi * 8]);
#pragma unroll
        for (int n = 0; n < 3; n++)
            b[n] = *reinterpret_cast<bf16x8*>(&Bs[(n * 16 + l15) * 40 + lhi * 8]);
#pragma unroll
        for (int m = 0; m < 2; m++)
#pragma unroll
            for (int n = 0; n < 3; n++)
                acc[m][n] = __builtin_amdgcn_mfma_f32_16x16x32_bf16(a[m], b[n], acc[m][n], 0, 0, 0);
    }
    // epilogue: bias + log_softmax per row (row lives in a 16-lane group)
    float b0 = bias[l15];
    float b1 = bias[16 + l15];
    float b2 = (l15 < 8) ? bias[32 + l15] : 0.f;
#pragma unroll
    for (int m = 0; m < 2; m++) {
#pragma unroll
        for (int j = 0; j < 4; j++) {
            int grow = row0 + w * 32 + m * 16 + lhi * 4 + j;
            float v0 = acc[m][0][j] + b0;
            float v1 = acc[m][1][j] + b1;
            float v2 = (l15 < 8) ? (acc[m][2][j] + b2) : -INFINITY;
            float mx = fmaxf(fmaxf(v0, v1), v2);
#pragma unroll
            for (int off = 1; off < 16; off <<= 1) mx = fmaxf(mx, __shfl_xor(mx, off, 64));
            float s = expf(v0 - mx) + expf(v1 - mx) + ((l15 < 8) ? expf(v2 - mx) : 0.f);
#pragma unroll
            for (int off = 1; off < 16; off <<= 1) s += __shfl_xor(s, off, 64);
            float lg = mx + logf(s);
            if (grow < N_NODES) {
                out[(size_t)grow * DOUT + l15] = v0 - lg;
                out[(size_t)grow * DOUT + 16 + l15] = v1 - lg;
                if (l15 < 8) out[(size_t)grow * DOUT + 32 + l15] = v2 - lg;
            }
        }
    }
}

__global__ void k_bnfin(const float* __restrict__ sum, const float* __restrict__ sumsq,
                        const float* __restrict__ g, const float* __restrict__ be,
                        float* __restrict__ scale, float* __restrict__ shift) {
    int c = threadIdx.x;
    if (c < DIM) {
        float mu = sum[c] * (1.0f / N_NODES);
        float var = sumsq[c] * (1.0f / N_NODES) - mu * mu;
        float sc = g[c] * rsqrtf(var + BN_EPS);
        scale[c] = sc;
        shift[c] = be[c] - mu * sc;
    }
}

// ---------------- launch ----------------
extern "C" void kernel_launch(void* const* d_in, const int* in_sizes, int n_in,
                              void* d_out, int out_size, void* d_ws, size_t ws_size,
                              hipStream_t stream) {
    const float* x = (const float*)d_in[0];
    const int* ei = (const int*)d_in[1];
    const float* w1 = (const float*)d_in[2];
    const float* r1 = (const float*)d_in[3];
    const float* b1 = (const float*)d_in[4];
    const float* g1 = (const float*)d_in[5];
    const float* be1 = (const float*)d_in[6];
    const float* w2 = (const float*)d_in[7];
    const float* r2 = (const float*)d_in[8];
    const float* b2 = (const float*)d_in[9];
    const float* g2 = (const float*)d_in[10];
    const float* be2 = (const float*)d_in[11];
    const float* w3 = (const float*)d_in[12];
    const float* r3 = (const float*)d_in[13];
    const float* b3 = (const float*)d_in[14];
    float* out = (float*)d_out;

    const size_t NF = (size_t)N_NODES * DIM;  // 12.8M
    ushort* Xb = (ushort*)d_ws;
    ushort* Ab = Xb + NF;
    ushort* Bb = Ab + NF;
    ushort* Wc1 = Bb + NF;             // 128*256
    ushort* Wc2 = Wc1 + 128 * 256;
    ushort* Wc3 = Wc2 + 128 * 256;     // 48*256
    uint* bucketbuf = (uint*)(Wc3 + 48 * 256);   // NB*BCAP = 2.048M uints
    int* gcnt = (int*)(bucketbuf + (size_t)NB * BCAP);  // NB
    int* bbase = gcnt + NB;                       // NB+1
    int* rowstart = bbase + NB + 1;               // N+1
    int* csr = rowstart + (N_NODES + 1);          // E
    float* colsum = (float*)(csr + N_EDGES);      // 128
    float* colsumsq = colsum + 128;
    float* scaleS = colsumsq + 128;
    float* shiftS = scaleS + 128;
    size_t needed = (size_t)((char*)(shiftS + 128) - (char*)d_ws);
    if (ws_size < needed) return;

    const int AGG_BLOCKS = N_NODES / 4;               // 25000
    const int GEMM_BLOCKS = (N_NODES + 127) / 128;    // 782

    // conversions
    k_cvt<<<2048, 256, 0, stream>>>(x, Xb, (int)(NF / 4));
    k_wcat<<<128, 256, 0, stream>>>(w1, r1, Wc1, 128);
    k_wcat<<<128, 256, 0, stream>>>(w2, r2, Wc2, 128);
    k_wcat<<<48, 256, 0, stream>>>(w3, r3, Wc3, DOUT);

    // CSR build (bucketed, 2-pass)
    hipMemsetAsync(gcnt, 0, sizeof(int) * NB, stream);
    k_bucket<<<256, 256, 0, stream>>>(ei, bucketbuf, gcnt);
    k_bscan<<<1, 64, 0, stream>>>(gcnt, bbase);
    k_csr_build<<<NB, 256, 0, stream>>>(ei, bucketbuf, gcnt, bbase, rowstart, csr);

    // ---- layer 1 ----  (h1 = gemm output, PRE-BN, stored in Ab; stats fused)
    k_agg_bf<<<AGG_BLOCKS, 256, 0, stream>>>(Xb, rowstart, csr, Ab, nullptr, nullptr, 0);
    hipMemsetAsync(colsum, 0, sizeof(float) * 256, stream);
    k_gemm_mfma<<<GEMM_BLOCKS, 256, 0, stream>>>(Ab, Xb, Wc1, b1, nullptr, nullptr, 0, Ab,
                                                 colsum, colsumsq, 1);
    k_bnfin<<<1, 128, 0, stream>>>(colsum, colsumsq, g1, be1, scaleS, shiftS);  // BN1

    // ---- layer 2 ----  (consumers apply BN1+ReLU on the fly; h2 PRE-BN in Bb; stats fused)
    k_agg_bf<<<AGG_BLOCKS, 256, 0, stream>>>(Ab, rowstart, csr, Bb, scaleS, shiftS, 1);
    hipMemsetAsync(colsum, 0, sizeof(float) * 256, stream);
    k_gemm_mfma<<<GEMM_BLOCKS, 256, 0, stream>>>(Bb, Ab, Wc2, b2, scaleS, shiftS, 1, Bb,
                                                 colsum, colsumsq, 1);
    k_bnfin<<<1, 128, 0, stream>>>(colsum, colsumsq, g2, be2, scaleS, shiftS);  // BN2

    // ---- layer 3 ----  (consumers apply BN2+ReLU; bias + log_softmax fused)
    k_agg_bf<<<AGG_BLOCKS, 256, 0, stream>>>(Bb, rowstart, csr, Ab, scaleS, shiftS, 1);
    k_gemm40_mfma<<<GEMM_BLOCKS, 256, 0, stream>>>(Ab, Bb, Wc3, b3, scaleS, shiftS, out);
}